// Round 1
// baseline (134.346 us; speedup 1.0000x reference)
//
#include <hip/hip_runtime.h>
#include <stdint.h>

typedef __attribute__((ext_vector_type(8))) short bf16x8;
typedef __attribute__((ext_vector_type(4))) float f32x4;

#define MFMA16(a, b, c) __builtin_amdgcn_mfma_f32_16x16x32_bf16((a), (b), (c), 0, 0, 0)

__device__ __forceinline__ void gload_lds16(const void* g, void* l) {
  __builtin_amdgcn_global_load_lds((const __attribute__((address_space(1))) void*)g,
                                   (__attribute__((address_space(3))) void*)l,
                                   16, 0, 0);
}

__device__ __forceinline__ unsigned short f2bf(float f) {
  union { float f; unsigned int u; } cv;
  cv.f = f;
  return (unsigned short)((cv.u + 0x7fffu + ((cv.u >> 16) & 1u)) >> 16);
}

#define BATCH 8192
#define ROWD  2128
#define HID   512
#define LATD  256
#define KP1   2176   // padded K for layer 1 (34*64)
#define NT1   67     // 67*32 = 2144 >= 2128

// ---------------- prep: transpose + cast (+ row permutation for W1) ----------------
// out[j][k] = bf16( in[map(k)][j] ), zero for k >= Kin.  in is [Kin_rows][J] row-major.
__global__ __launch_bounds__(256) void ASAECF_tcast(
    const float* __restrict__ in, unsigned short* __restrict__ out,
    int J, int Kin, int Kp, int permute)
{
  __shared__ float tile[64][65];
  const int k0 = blockIdx.x * 64, j0 = blockIdx.y * 64;
  const int t = threadIdx.x;
#pragma unroll
  for (int i = 0; i < 16; ++i) {
    int lin = i * 256 + t;
    int kk = lin >> 6, jj = lin & 63;
    int k = k0 + kk;
    float v = 0.0f;
    if (k < Kin) {
      int src = permute ? (k < 128 ? k + 2000 : k - 128) : k;
      v = in[(size_t)src * J + j0 + jj];
    }
    tile[kk][jj] = v;
  }
  __syncthreads();
#pragma unroll
  for (int i = 0; i < 16; ++i) {
    int lin = i * 256 + t;
    int jj = lin >> 6, kk = lin & 63;
    out[(size_t)(j0 + jj) * Kp + k0 + kk] = f2bf(tile[kk][jj]);
  }
}

// ---------------- GEMM1: h = relu(gather(look) @ W1p + b1), bf16 out ----------------
// BM=64, BN=512 (all of N), BK=32, 8 waves (1x8), double-buffered LDS.
__global__ __launch_bounds__(512) void ASAECF_gemm1(
    const int* __restrict__ x,
    const float* __restrict__ ulook, const float* __restrict__ ilook,
    const unsigned short* __restrict__ w1pt,   // [2][512][KP1]
    const float* __restrict__ ub1, const float* __restrict__ ib1,
    unsigned short* __restrict__ hbuf)         // [2][8192][512]
{
  const int tower = blockIdx.z;
  const float* __restrict__ look = tower ? ilook : ulook;
  const unsigned short* __restrict__ w1 = w1pt + (size_t)tower * HID * KP1;
  const float* __restrict__ b1 = tower ? ib1 : ub1;
  unsigned short* __restrict__ hout = hbuf + (size_t)tower * BATCH * HID;

  __shared__ unsigned short Ab[2][64 * 32];    // [row][k]   4 KiB each
  __shared__ unsigned short Bb[2][512 * 32];   // [col][k]  32 KiB each

  const int tid  = threadIdx.x;
  const int lane = tid & 63;
  const int wid  = tid >> 6;
  const int fr   = lane & 15;
  const int fq   = lane >> 4;
  const int row0 = blockIdx.x * 64;

  // A staging coords: thread -> (row, 4 consecutive k)
  const int ar = tid >> 3;
  const int ak = (tid & 7) * 4;
  const long long arow = (long long)x[(row0 + ar) * 2 + tower] * ROWD + ak;

  f32x4 acc[4][4] = {};

  // ---- prologue: stage tile 0 into buffer 0 ----
  {
    float4 av = *(const float4*)(look + arow);   // k0=0 always valid (ak <= 28)
    unsigned int lo = (unsigned)f2bf(av.x) | ((unsigned)f2bf(av.y) << 16);
    unsigned int hi = (unsigned)f2bf(av.z) | ((unsigned)f2bf(av.w) << 16);
    uint2 p; p.x = lo; p.y = hi;
    *(uint2*)&Ab[0][ar * 32 + ak] = p;
#pragma unroll
    for (int i = 0; i < 4; ++i) {
      int off = (wid * 4 + i) * 1024 + lane * 16;   // byte offset in Bb
      int j = off >> 6, kb = off & 63;
      gload_lds16(w1 + (size_t)j * KP1 + (kb >> 1), (char*)&Bb[0][0] + off);
    }
  }

  int cur = 0;
  for (int t = 0; t < NT1; ++t) {
    __syncthreads();   // buf[cur] ready (drains vmcnt+lgkm)

    const int tn = t + 1;
    const bool pre = (tn < NT1);
    float4 av = {0.0f, 0.0f, 0.0f, 0.0f};
    if (pre) {
      const int k0n = tn * 32;
      if (k0n + ak + 3 < ROWD) av = *(const float4*)(look + arow + k0n);
#pragma unroll
      for (int i = 0; i < 4; ++i) {
        int off = (wid * 4 + i) * 1024 + lane * 16;
        int j = off >> 6, kb = off & 63;
        gload_lds16(w1 + (size_t)j * KP1 + k0n + (kb >> 1), (char*)&Bb[cur ^ 1][0] + off);
      }
    }

    // ---- compute on buf[cur] ----
    bf16x8 af[4], bg[4];
#pragma unroll
    for (int m = 0; m < 4; ++m)
      af[m] = *(const bf16x8*)&Ab[cur][(m * 16 + fr) * 32 + fq * 8];
#pragma unroll
    for (int n = 0; n < 4; ++n)
      bg[n] = *(const bf16x8*)&Bb[cur][(wid * 64 + n * 16 + fr) * 32 + fq * 8];
#pragma unroll
    for (int m = 0; m < 4; ++m)
#pragma unroll
      for (int n = 0; n < 4; ++n)
        acc[m][n] = MFMA16(af[m], bg[n], acc[m][n]);

    // ---- deferred A write (hides gather latency under the MFMAs) ----
    if (pre) {
      unsigned int lo = (unsigned)f2bf(av.x) | ((unsigned)f2bf(av.y) << 16);
      unsigned int hi = (unsigned)f2bf(av.z) | ((unsigned)f2bf(av.w) << 16);
      uint2 p; p.x = lo; p.y = hi;
      *(uint2*)&Ab[cur ^ 1][ar * 32 + ak] = p;
    }
    cur ^= 1;
  }

  // ---- epilogue: + bias, relu, bf16 store ----
#pragma unroll
  for (int n = 0; n < 4; ++n) {
    const int col = wid * 64 + n * 16 + fr;
    const float bb = b1[col];
#pragma unroll
    for (int m = 0; m < 4; ++m) {
#pragma unroll
      for (int i = 0; i < 4; ++i) {
        const int r = row0 + m * 16 + fq * 4 + i;
        float v = acc[m][n][i] + bb;
        v = fmaxf(v, 0.0f);
        hout[(size_t)r * HID + col] = f2bf(v);
      }
    }
  }
}

// ---------------- GEMM2: u/v = h @ W2 + b2 (f32 out) ----------------
// BM=64, BN=256 (all of N), BK=64, 8 waves (1x8), double-buffered LDS.
__global__ __launch_bounds__(512) void ASAECF_gemm2(
    const unsigned short* __restrict__ hbuf,   // [2][8192][512]
    const unsigned short* __restrict__ w2t,    // [2][256][512]
    const float* __restrict__ ub2, const float* __restrict__ ib2,
    float* __restrict__ uv)                    // [2][8192][256]
{
  const int tower = blockIdx.z;
  const unsigned short* __restrict__ hp = hbuf + (size_t)tower * BATCH * HID;
  const unsigned short* __restrict__ w2 = w2t + (size_t)tower * LATD * HID;
  const float* __restrict__ b2 = tower ? ib2 : ub2;
  float* __restrict__ uvp = uv + (size_t)tower * BATCH * LATD;

  __shared__ unsigned short Ab[2][64 * 64];    // [row][k]   8 KiB each
  __shared__ unsigned short Bb[2][256 * 64];   // [col][k]  32 KiB each

  const int tid  = threadIdx.x;
  const int lane = tid & 63;
  const int wid  = tid >> 6;
  const int fr   = lane & 15;
  const int fq   = lane >> 4;
  const int row0 = blockIdx.x * 64;

  f32x4 acc[4][2] = {};

  auto do_stage = [&](int buf, int t) {
    const int k0 = t * 64;
    {
      int off = wid * 1024 + lane * 16;          // A: 8 KiB -> 1 issue/wave
      int r = off >> 7, kb = off & 127;
      gload_lds16(hp + (size_t)(row0 + r) * HID + k0 + (kb >> 1), (char*)&Ab[buf][0] + off);
    }
#pragma unroll
    for (int i = 0; i < 4; ++i) {                // B: 32 KiB -> 4 issues/wave
      int off = (wid * 4 + i) * 1024 + lane * 16;
      int j = off >> 7, kb = off & 127;
      gload_lds16(w2 + (size_t)j * HID + k0 + (kb >> 1), (char*)&Bb[buf][0] + off);
    }
  };

  do_stage(0, 0);
  int cur = 0;
  for (int t = 0; t < 8; ++t) {
    __syncthreads();
    if (t + 1 < 8) do_stage(cur ^ 1, t + 1);
#pragma unroll
    for (int ks = 0; ks < 2; ++ks) {
      bf16x8 af[4], bg[2];
#pragma unroll
      for (int m = 0; m < 4; ++m)
        af[m] = *(const bf16x8*)&Ab[cur][(m * 16 + fr) * 64 + ks * 32 + fq * 8];
#pragma unroll
      for (int n = 0; n < 2; ++n)
        bg[n] = *(const bf16x8*)&Bb[cur][(wid * 32 + n * 16 + fr) * 64 + ks * 32 + fq * 8];
#pragma unroll
      for (int m = 0; m < 4; ++m)
#pragma unroll
        for (int n = 0; n < 2; ++n)
          acc[m][n] = MFMA16(af[m], bg[n], acc[m][n]);
    }
    cur ^= 1;
  }

#pragma unroll
  for (int n = 0; n < 2; ++n) {
    const int col = wid * 32 + n * 16 + fr;
    const float bb = b2[col];
#pragma unroll
    for (int m = 0; m < 4; ++m) {
#pragma unroll
      for (int i = 0; i < 4; ++i) {
        const int r = row0 + m * 16 + fq * 4 + i;
        uvp[(size_t)r * LATD + col] = acc[m][n][i] + bb;
      }
    }
  }
}

// ---------------- final: out[b] = dot(u[b,:], v[b,:]) ----------------
__global__ __launch_bounds__(256) void ASAECF_dot(
    const float* __restrict__ uv, float* __restrict__ out)
{
  const int tid = threadIdx.x, wid = tid >> 6, lane = tid & 63;
  const int row = blockIdx.x * 4 + wid;
  const float4* u4 = (const float4*)(uv + (size_t)row * LATD);
  const float4* v4 = (const float4*)(uv + (size_t)BATCH * LATD + (size_t)row * LATD);
  float4 a = u4[lane];
  float4 b = v4[lane];
  float s = a.x * b.x + a.y * b.y + a.z * b.z + a.w * b.w;
#pragma unroll
  for (int o = 32; o > 0; o >>= 1) s += __shfl_xor(s, o, 64);
  if (lane == 0) out[row] = s;
}

extern "C" void kernel_launch(void* const* d_in, const int* in_sizes, int n_in,
                              void* d_out, int out_size, void* d_ws, size_t ws_size,
                              hipStream_t stream) {
  (void)in_sizes; (void)n_in; (void)out_size; (void)ws_size;
  const int*   x     = (const int*)d_in[0];
  const float* ulook = (const float*)d_in[1];
  const float* ilook = (const float*)d_in[2];
  const float* uW1   = (const float*)d_in[3];
  const float* ub1   = (const float*)d_in[4];
  const float* uW2   = (const float*)d_in[5];
  const float* ub2   = (const float*)d_in[6];
  const float* iW1   = (const float*)d_in[7];
  const float* ib1   = (const float*)d_in[8];
  const float* iW2   = (const float*)d_in[9];
  const float* ib2   = (const float*)d_in[10];
  float* out = (float*)d_out;

  // workspace layout (bytes):
  //   w1pt: [2][512][2176] bf16  = 4,456,448
  //   w2t : [2][256][512]  bf16  =   524,288   @ 4,456,448
  //   h   : [2][8192][512] bf16  = 16,777,216  @ 4,980,736
  //   uv  : [2][8192][256] f32   = 16,777,216  @ 21,757,952
  char* ws = (char*)d_ws;
  unsigned short* w1pt = (unsigned short*)(ws);
  unsigned short* w2t  = (unsigned short*)(ws + 4456448);
  unsigned short* hbuf = (unsigned short*)(ws + 4980736);
  float*          uv   = (float*)(ws + 21757952);

  ASAECF_tcast<<<dim3(34, 8), 256, 0, stream>>>(uW1, w1pt,             512, ROWD, KP1, 1);
  ASAECF_tcast<<<dim3(34, 8), 256, 0, stream>>>(iW1, w1pt + 512 * KP1, 512, ROWD, KP1, 1);
  ASAECF_tcast<<<dim3(8, 4),  256, 0, stream>>>(uW2, w2t,              256, HID,  HID, 0);
  ASAECF_tcast<<<dim3(8, 4),  256, 0, stream>>>(iW2, w2t + 256 * HID,  256, HID,  HID, 0);

  ASAECF_gemm1<<<dim3(128, 1, 2), 512, 0, stream>>>(x, ulook, ilook, w1pt, ub1, ib1, hbuf);
  ASAECF_gemm2<<<dim3(128, 1, 2), 512, 0, stream>>>(hbuf, w2t, ub2, ib2, uv);
  ASAECF_dot<<<dim3(2048), 256, 0, stream>>>(uv, out);
}

// Round 2
// 106.653 us; speedup vs baseline: 1.2597x; 1.2597x over previous
//
#include <hip/hip_runtime.h>
#include <stdint.h>

typedef __attribute__((ext_vector_type(8))) short bf16x8;
typedef __attribute__((ext_vector_type(4))) float f32x4;

#define MFMA16(a, b, c) __builtin_amdgcn_mfma_f32_16x16x32_bf16((a), (b), (c), 0, 0, 0)

static __device__ __forceinline__ unsigned short f2bf(float f) {
  union { float f; unsigned int u; } cv;
  cv.f = f;
  return (unsigned short)((cv.u + 0x7fffu + ((cv.u >> 16) & 1u)) >> 16);
}

#define BATCH 8192
#define ROWD  2128
#define HID   512
#define LATD  256
#define KC1   272           // 8-elem k-chunks for layer 1 (272*8 = 2176, zero-padded)
#define NT1   67            // 32-k tiles actually computed (67*32 = 2144 >= 2128)
#define HSL_TW (BATCH * HID)  // ushorts per tower in h_sl

// ---------- prep: k-chunked transpose-cast ----------
// out[tower][kc][n][e] = bf16( in[perm(kc*8+e)][n] ), 0 beyond Kin.
__global__ __launch_bounds__(256) void ASAECF_tcast(
    const float* __restrict__ in0, const float* __restrict__ in1,
    unsigned short* __restrict__ out, int N, int lgN, int Kin, int KC, int perm)
{
  const float* __restrict__ in = blockIdx.z ? in1 : in0;
  unsigned short* __restrict__ o = out + (size_t)blockIdx.z * KC * N * 8;
  const int s = blockIdx.x * 256 + threadIdx.x;   // slot index
  const int kc = s >> lgN, n = s & (N - 1);
  unsigned short v[8];
#pragma unroll
  for (int e = 0; e < 8; ++e) {
    const int k = kc * 8 + e;
    float f = 0.0f;
    if (k < Kin) {
      const int src = perm ? (k < 128 ? k + 2000 : k - 128) : k;
      f = in[(size_t)src * N + n];
    }
    v[e] = f2bf(f);
  }
  *(uint4*)(o + (size_t)s * 8) = *(const uint4*)v;
}

// ---------- GEMM1: h = relu(gather(look) @ W1p + b1) ----------
// BM=64, BN=512 (full N), BK=32. 8 waves, wave tile 64x64.
// B fragments read directly from global (L2-resident, pre-swizzled w1s).
// A double-buffered in LDS with 80-B padded rows (conflict-free).
__global__ __launch_bounds__(512, 2) void ASAECF_gemm1(
    const int* __restrict__ x,
    const float* __restrict__ ulook, const float* __restrict__ ilook,
    const unsigned short* __restrict__ w1s,   // [2][KC1][512][8]
    const float* __restrict__ ub1, const float* __restrict__ ib1,
    unsigned short* __restrict__ hsl)         // [2][rb64][kc][row64][8]
{
  const int tower = blockIdx.z;
  const float* __restrict__ look = tower ? ilook : ulook;
  const unsigned short* __restrict__ w1 = w1s + (size_t)tower * KC1 * HID * 8;
  const float* __restrict__ b1 = tower ? ib1 : ub1;
  unsigned short* __restrict__ hout = hsl + (size_t)tower * HSL_TW;

  __shared__ unsigned short Ab[2][64 * 40];   // 64 rows x 32 k, 80-B padded rows

  const int tid  = threadIdx.x;
  const int lane = tid & 63, wid = tid >> 6;
  const int fr   = lane & 15, fq = lane >> 4;
  const int row0 = blockIdx.x * 64;

  // A staging: thread -> (row ar, 4 consecutive k at ak)
  const int ar = tid >> 3, ak = (tid & 7) * 4;
  const long long arow = (long long)x[(row0 + ar) * 2 + tower] * ROWD + ak;

  // B fragment offsets within one k-tile slab (4*512*8 ushorts)
  int boff[4];
#pragma unroll
  for (int n = 0; n < 4; ++n)
    boff[n] = (fq * 512 + wid * 64 + n * 16 + fr) * 8;

  f32x4 acc[4][4] = {};

  // prologue: stage A tile 0
  {
    float4 av = *(const float4*)(look + arow);
    uint2 p;
    p.x = (unsigned)f2bf(av.x) | ((unsigned)f2bf(av.y) << 16);
    p.y = (unsigned)f2bf(av.z) | ((unsigned)f2bf(av.w) << 16);
    *(uint2*)&Ab[0][ar * 40 + ak] = p;
  }

  int cur = 0;
  for (int t = 0; t < NT1; ++t) {
    __syncthreads();   // Ab[cur] ready

    // B fragments for tile t (global -> regs, lands under the A reads)
    const unsigned short* bp = w1 + (size_t)t * (4 * 512 * 8);
    bf16x8 bg[4];
#pragma unroll
    for (int n = 0; n < 4; ++n) bg[n] = *(const bf16x8*)(bp + boff[n]);

    // A gather for tile t+1 (issue early, write late)
    float4 av = {0.0f, 0.0f, 0.0f, 0.0f};
    const bool pre = (t + 1 < NT1);
    if (pre) {
      const int k0 = (t + 1) * 32;
      if (k0 + ak <= ROWD - 4) av = *(const float4*)(look + arow + k0);
    }

    bf16x8 af[4];
#pragma unroll
    for (int m = 0; m < 4; ++m)
      af[m] = *(const bf16x8*)&Ab[cur][(m * 16 + fr) * 40 + fq * 8];
#pragma unroll
    for (int n = 0; n < 4; ++n)
#pragma unroll
      for (int m = 0; m < 4; ++m)
        acc[m][n] = MFMA16(af[m], bg[n], acc[m][n]);

    if (pre) {
      uint2 p;
      p.x = (unsigned)f2bf(av.x) | ((unsigned)f2bf(av.y) << 16);
      p.y = (unsigned)f2bf(av.z) | ((unsigned)f2bf(av.w) << 16);
      *(uint2*)&Ab[cur ^ 1][ar * 40 + ak] = p;
    }
    cur ^= 1;
  }

  // epilogue: bias + relu + store h in k-chunked slot layout
#pragma unroll
  for (int n = 0; n < 4; ++n) {
    const int col = wid * 64 + n * 16 + fr;
    const int kc = col >> 3, e = col & 7;
    const float bb = b1[col];
    unsigned short* hb = hout + (((size_t)blockIdx.x * 64 + kc) * 64) * 8 + e;
#pragma unroll
    for (int m = 0; m < 4; ++m)
#pragma unroll
      for (int i = 0; i < 4; ++i) {
        const int row = m * 16 + fq * 4 + i;
        const float v = fmaxf(acc[m][n][i] + bb, 0.0f);
        hb[row * 8] = f2bf(v);
      }
  }
}

// ---------- GEMM2 + dot, fully fused, no LDS staging ----------
// BM=32, both towers per block, 8 waves, wave covers 32 cols of both towers.
__global__ __launch_bounds__(512, 2) void ASAECF_gemm2dot(
    const unsigned short* __restrict__ hsl,   // [2][rb64][kc][row64][8]
    const unsigned short* __restrict__ w2s,   // [2][64][256][8]
    const float* __restrict__ ub2, const float* __restrict__ ib2,
    float* __restrict__ out)
{
  const int tid  = threadIdx.x;
  const int lane = tid & 63, wid = tid >> 6;
  const int fr   = lane & 15, fq = lane >> 4;
  const int rb   = blockIdx.x;          // 32-row block
  const int row0 = rb * 32;

  const unsigned short* __restrict__ hu = hsl;
  const unsigned short* __restrict__ hv = hsl + (size_t)HSL_TW;
  const size_t abase = ((size_t)(rb >> 1) * 64) * 64 * 8;
  const int lrow0 = (rb & 1) * 32;

  f32x4 au[2][2] = {}, av[2][2] = {};

#pragma unroll
  for (int t = 0; t < 8; ++t) {
#pragma unroll
    for (int s = 0; s < 2; ++s) {
      const int kc = t * 8 + s * 4 + fq;
      bf16x8 a_u[2], a_v[2], b_u[2], b_v[2];
#pragma unroll
      for (int m = 0; m < 2; ++m) {
        const size_t off = abase + ((size_t)kc * 64 + lrow0 + m * 16 + fr) * 8;
        a_u[m] = *(const bf16x8*)(hu + off);
        a_v[m] = *(const bf16x8*)(hv + off);
      }
#pragma unroll
      for (int n = 0; n < 2; ++n) {
        const int col = wid * 32 + n * 16 + fr;
        const size_t offb = ((size_t)kc * 256 + col) * 8;
        b_u[n] = *(const bf16x8*)(w2s + offb);
        b_v[n] = *(const bf16x8*)(w2s + (size_t)64 * 256 * 8 + offb);
      }
#pragma unroll
      for (int m = 0; m < 2; ++m)
#pragma unroll
        for (int n = 0; n < 2; ++n) {
          au[m][n] = MFMA16(a_u[m], b_u[n], au[m][n]);
          av[m][n] = MFMA16(a_v[m], b_v[n], av[m][n]);
        }
    }
  }

  // bias + per-row dot + reduction
  __shared__ float red[8][32];
  float bu[2], bv[2];
#pragma unroll
  for (int n = 0; n < 2; ++n) {
    const int col = wid * 32 + n * 16 + fr;
    bu[n] = ub2[col];
    bv[n] = ib2[col];
  }
#pragma unroll
  for (int m = 0; m < 2; ++m)
#pragma unroll
    for (int i = 0; i < 4; ++i) {
      float p = 0.0f;
#pragma unroll
      for (int n = 0; n < 2; ++n)
        p += (au[m][n][i] + bu[n]) * (av[m][n][i] + bv[n]);
      p += __shfl_xor(p, 1, 64);
      p += __shfl_xor(p, 2, 64);
      p += __shfl_xor(p, 4, 64);
      p += __shfl_xor(p, 8, 64);
      if (fr == 0) red[wid][m * 16 + fq * 4 + i] = p;
    }
  __syncthreads();
  if (tid < 32) {
    float s = 0.0f;
#pragma unroll
    for (int w = 0; w < 8; ++w) s += red[w][tid];
    out[row0 + tid] = s;
  }
}

extern "C" void kernel_launch(void* const* d_in, const int* in_sizes, int n_in,
                              void* d_out, int out_size, void* d_ws, size_t ws_size,
                              hipStream_t stream) {
  (void)in_sizes; (void)n_in; (void)out_size; (void)ws_size;
  const int*   x     = (const int*)d_in[0];
  const float* ulook = (const float*)d_in[1];
  const float* ilook = (const float*)d_in[2];
  const float* uW1   = (const float*)d_in[3];
  const float* ub1   = (const float*)d_in[4];
  const float* uW2   = (const float*)d_in[5];
  const float* ub2   = (const float*)d_in[6];
  const float* iW1   = (const float*)d_in[7];
  const float* ib1   = (const float*)d_in[8];
  const float* iW2   = (const float*)d_in[9];
  const float* ib2   = (const float*)d_in[10];
  float* out = (float*)d_out;

  // workspace layout (bytes):
  //   w1s: [2][272][512][8] bf16 = 4,456,448
  //   w2s: [2][64][256][8]  bf16 =   524,288  @ 4,456,448
  //   hsl: [2][8192*512]    bf16 = 16,777,216 @ 4,980,736
  char* ws = (char*)d_ws;
  unsigned short* w1s = (unsigned short*)(ws);
  unsigned short* w2s = (unsigned short*)(ws + 4456448);
  unsigned short* hsl = (unsigned short*)(ws + 4980736);

  ASAECF_tcast<<<dim3(544, 1, 2), 256, 0, stream>>>(uW1, iW1, w1s, 512, 9, ROWD, KC1, 1);
  ASAECF_tcast<<<dim3(64, 1, 2),  256, 0, stream>>>(uW2, iW2, w2s, 256, 8, HID, 64, 0);
  ASAECF_gemm1<<<dim3(128, 1, 2), 512, 0, stream>>>(x, ulook, ilook, w1s, ub1, ib1, hsl);
  ASAECF_gemm2dot<<<dim3(256), 512, 0, stream>>>(hsl, w2s, ub2, ib2, out);
}

// Round 4
// 89.372 us; speedup vs baseline: 1.5032x; 1.1934x over previous
//
#include <hip/hip_runtime.h>
#include <stdint.h>

typedef __attribute__((ext_vector_type(8))) short bf16x8;
typedef __attribute__((ext_vector_type(4))) float f32x4;

#define MFMA16(a, b, c) __builtin_amdgcn_mfma_f32_16x16x32_bf16((a), (b), (c), 0, 0, 0)

static __device__ __forceinline__ unsigned short f2bf(float f) {
  union { float f; unsigned int u; } cv;
  cv.f = f;
  return (unsigned short)((cv.u + 0x7fffu + ((cv.u >> 16) & 1u)) >> 16);
}

#define BATCH 8192
#define ROWD  2128
#define HID   512
#define LATD  256
#define KC1   272            // 8-elem k-chunks for layer 1 (272*8 = 2176, zero-padded)
#define NT1   68             // 32-k tiles (68*32 = 2176; trailing tiles are zero-padded)
#define HSL_TW (BATCH * HID) // ushorts per tower in h_sl

// ---------- prep: k-chunked transpose-cast ----------
// out[tower][kc][n][e] = bf16( in[perm(kc*8+e)][n] ), 0 beyond Kin.
__global__ __launch_bounds__(256) void ASAECF_tcast(
    const float* __restrict__ in0, const float* __restrict__ in1,
    unsigned short* __restrict__ out, int N, int lgN, int Kin, int KC, int perm)
{
  const float* __restrict__ in = blockIdx.z ? in1 : in0;
  unsigned short* __restrict__ o = out + (size_t)blockIdx.z * KC * N * 8;
  const int s = blockIdx.x * 256 + threadIdx.x;   // slot index
  const int kc = s >> lgN, n = s & (N - 1);
  unsigned short v[8];
#pragma unroll
  for (int e = 0; e < 8; ++e) {
    const int k = kc * 8 + e;
    float f = 0.0f;
    if (k < Kin) {
      const int src = perm ? (k < 128 ? k + 2000 : k - 128) : k;
      f = in[(size_t)src * N + n];
    }
    v[e] = f2bf(f);
  }
  *(uint4*)(o + (size_t)s * 8) = *(const uint4*)v;
}

// ---------- GEMM1: h = relu(gather(look) @ W1p + b1) ----------
// BM=64, BN=512 (full N), BK=32. 8 waves, wave tile 64x64.
// B fragments: global (L2-resident w1s), prefetched 1 tile ahead into regs.
// A: random-row gather pipelined 2 tiles ahead in regs, LDS double-buffered.
__global__ __launch_bounds__(512) void ASAECF_gemm1(
    const int* __restrict__ x,
    const float* __restrict__ ulook, const float* __restrict__ ilook,
    const unsigned short* __restrict__ w1s,   // [2][KC1][512][8]
    const float* __restrict__ ub1, const float* __restrict__ ib1,
    unsigned short* __restrict__ hsl)         // [2][rb64][kc][row64][8]
{
  // tower<->XCD partition: XCDs 0-3 -> tower 0, XCDs 4-7 -> tower 1
  const int bid   = blockIdx.x;
  const int xcd   = bid & 7;
  const int tower = xcd >> 2;
  const int rb    = (bid >> 3) * 4 + (xcd & 3);

  const float* __restrict__ look = tower ? ilook : ulook;
  const unsigned short* __restrict__ w1 = w1s + (size_t)tower * KC1 * HID * 8;
  const float* __restrict__ b1 = tower ? ib1 : ub1;
  unsigned short* __restrict__ hout = hsl + (size_t)tower * HSL_TW;

  __shared__ unsigned short Ab[2][64 * 40];   // 64 rows x 32 k, 80-B padded rows

  const int tid  = threadIdx.x;
  const int lane = tid & 63, wid = tid >> 6;
  const int fr   = lane & 15, fq = lane >> 4;
  const int row0 = rb * 64;

  // A staging: thread -> (row ar, 4 consecutive k at ak)
  const int ar = tid >> 3, ak = (tid & 7) * 4;
  const long long arow = (long long)x[(row0 + ar) * 2 + tower] * ROWD + ak;

  // B fragment offsets within one k-tile slab (4*512*8 ushorts)
  int boff[4];
#pragma unroll
  for (int n = 0; n < 4; ++n)
    boff[n] = (fq * 512 + wid * 64 + n * 16 + fr) * 8;

  auto loadA = [&](int tt) -> f32x4 {
    f32x4 v = {0.0f, 0.0f, 0.0f, 0.0f};
    if (tt * 32 + ak <= ROWD - 4)
      v = __builtin_nontemporal_load((const f32x4*)(look + arow + tt * 32));
    return v;
  };
  auto writeA = [&](int buf, f32x4 v) {
    uint2 p;
    p.x = (unsigned)f2bf(v[0]) | ((unsigned)f2bf(v[1]) << 16);
    p.y = (unsigned)f2bf(v[2]) | ((unsigned)f2bf(v[3]) << 16);
    *(uint2*)&Ab[buf][ar * 40 + ak] = p;
  };

  f32x4 acc[4][4] = {};
  bf16x8 bgc[4], bgn[4];
  f32x4 rA0, rA1;

  // prologue: A(0) -> Ab[0]; A(1),A(2) in flight; B(0) in flight
  writeA(0, loadA(0));
  rA0 = loadA(1);
  rA1 = loadA(2);
#pragma unroll
  for (int n = 0; n < 4; ++n) bgc[n] = *(const bf16x8*)(w1 + boff[n]);

#pragma unroll 2
  for (int t = 0; t < NT1; ++t) {
    __syncthreads();   // Ab[t&1] ready
    const int cu = t & 1;

    // B prefetch for t+1 (stays in flight through this tile's MFMAs)
    const unsigned short* bpn = w1 + (size_t)(t + 1) * (4 * 512 * 8);
#pragma unroll
    for (int n = 0; n < 4; ++n) bgn[n] = *(const bf16x8*)(bpn + boff[n]);

    bf16x8 af[4];
#pragma unroll
    for (int m = 0; m < 4; ++m)
      af[m] = *(const bf16x8*)&Ab[cu][(m * 16 + fr) * 40 + fq * 8];
#pragma unroll
    for (int n = 0; n < 4; ++n)
#pragma unroll
      for (int m = 0; m < 4; ++m)
        acc[m][n] = MFMA16(af[m], bgc[n], acc[m][n]);

    // deferred A write (data loaded 2 tiles ago), then refill the slot
    if (cu == 0) { writeA(1, rA0); rA0 = loadA(t + 3); }
    else         { writeA(0, rA1); rA1 = loadA(t + 3); }

#pragma unroll
    for (int n = 0; n < 4; ++n) bgc[n] = bgn[n];
  }

  // epilogue: bias + relu + store h in k-chunked slot layout
#pragma unroll
  for (int n = 0; n < 4; ++n) {
    const int col = wid * 64 + n * 16 + fr;
    const int kc = col >> 3, e = col & 7;
    const float bb = b1[col];
    unsigned short* hb = hout + (((size_t)rb * 64 + kc) * 64) * 8 + e;
#pragma unroll
    for (int m = 0; m < 4; ++m)
#pragma unroll
      for (int i = 0; i < 4; ++i) {
        const int row = m * 16 + fq * 4 + i;
        const float v = fmaxf(acc[m][n][i] + bb, 0.0f);
        hb[row * 8] = f2bf(v);
      }
  }
}

// ---------- GEMM2 + dot, fully fused, no LDS staging ----------
// BM=32, both towers per block, 8 waves, wave covers 32 cols of both towers.
__global__ __launch_bounds__(512, 2) void ASAECF_gemm2dot(
    const unsigned short* __restrict__ hsl,   // [2][rb64][kc][row64][8]
    const unsigned short* __restrict__ w2s,   // [2][64][256][8]
    const float* __restrict__ ub2, const float* __restrict__ ib2,
    float* __restrict__ out)
{
  const int tid  = threadIdx.x;
  const int lane = tid & 63, wid = tid >> 6;
  const int fr   = lane & 15, fq = lane >> 4;
  const int rb   = blockIdx.x;          // 32-row block
  const int row0 = rb * 32;

  const unsigned short* __restrict__ hu = hsl;
  const unsigned short* __restrict__ hv = hsl + (size_t)HSL_TW;
  const size_t abase = ((size_t)(rb >> 1) * 64) * 64 * 8;
  const int lrow0 = (rb & 1) * 32;

  f32x4 au[2][2] = {}, av[2][2] = {};

#pragma unroll
  for (int t = 0; t < 8; ++t) {
#pragma unroll
    for (int s = 0; s < 2; ++s) {
      const int kc = t * 8 + s * 4 + fq;
      bf16x8 a_u[2], a_v[2], b_u[2], b_v[2];
#pragma unroll
      for (int m = 0; m < 2; ++m) {
        const size_t off = abase + ((size_t)kc * 64 + lrow0 + m * 16 + fr) * 8;
        a_u[m] = *(const bf16x8*)(hu + off);
        a_v[m] = *(const bf16x8*)(hv + off);
      }
#pragma unroll
      for (int n = 0; n < 2; ++n) {
        const int col = wid * 32 + n * 16 + fr;
        const size_t offb = ((size_t)kc * 256 + col) * 8;
        b_u[n] = *(const bf16x8*)(w2s + offb);
        b_v[n] = *(const bf16x8*)(w2s + (size_t)64 * 256 * 8 + offb);
      }
#pragma unroll
      for (int m = 0; m < 2; ++m)
#pragma unroll
        for (int n = 0; n < 2; ++n) {
          au[m][n] = MFMA16(a_u[m], b_u[n], au[m][n]);
          av[m][n] = MFMA16(a_v[m], b_v[n], av[m][n]);
        }
    }
  }

  // bias + per-row dot + reduction
  __shared__ float red[8][32];
  float bu[2], bv[2];
#pragma unroll
  for (int n = 0; n < 2; ++n) {
    const int col = wid * 32 + n * 16 + fr;
    bu[n] = ub2[col];
    bv[n] = ib2[col];
  }
#pragma unroll
  for (int m = 0; m < 2; ++m)
#pragma unroll
    for (int i = 0; i < 4; ++i) {
      float p = 0.0f;
#pragma unroll
      for (int n = 0; n < 2; ++n)
        p += (au[m][n][i] + bu[n]) * (av[m][n][i] + bv[n]);
      p += __shfl_xor(p, 1, 64);
      p += __shfl_xor(p, 2, 64);
      p += __shfl_xor(p, 4, 64);
      p += __shfl_xor(p, 8, 64);
      if (fr == 0) red[wid][m * 16 + fq * 4 + i] = p;
    }
  __syncthreads();
  if (tid < 32) {
    float s = 0.0f;
#pragma unroll
    for (int w = 0; w < 8; ++w) s += red[w][tid];
    out[row0 + tid] = s;
  }
}

extern "C" void kernel_launch(void* const* d_in, const int* in_sizes, int n_in,
                              void* d_out, int out_size, void* d_ws, size_t ws_size,
                              hipStream_t stream) {
  (void)in_sizes; (void)n_in; (void)out_size; (void)ws_size;
  const int*   x     = (const int*)d_in[0];
  const float* ulook = (const float*)d_in[1];
  const float* ilook = (const float*)d_in[2];
  const float* uW1   = (const float*)d_in[3];
  const float* ub1   = (const float*)d_in[4];
  const float* uW2   = (const float*)d_in[5];
  const float* ub2   = (const float*)d_in[6];
  const float* iW1   = (const float*)d_in[7];
  const float* ib1   = (const float*)d_in[8];
  const float* iW2   = (const float*)d_in[9];
  const float* ib2   = (const float*)d_in[10];
  float* out = (float*)d_out;

  // workspace layout (bytes):
  //   w1s: [2][272][512][8] bf16 = 4,456,448
  //   w2s: [2][64][256][8]  bf16 =   524,288  @ 4,456,448
  //   hsl: [2][8192*512]    bf16 = 16,777,216 @ 4,980,736
  char* ws = (char*)d_ws;
  unsigned short* w1s = (unsigned short*)(ws);
  unsigned short* w2s = (unsigned short*)(ws + 4456448);
  unsigned short* hsl = (unsigned short*)(ws + 4980736);

  ASAECF_tcast<<<dim3(544, 1, 2), 256, 0, stream>>>(uW1, iW1, w1s, 512, 9, ROWD, KC1, 1);
  ASAECF_tcast<<<dim3(64, 1, 2),  256, 0, stream>>>(uW2, iW2, w2s, 256, 8, HID, 64, 0);
  ASAECF_gemm1<<<dim3(256), 512, 0, stream>>>(x, ulook, ilook, w1s, ub1, ib1, hsl);
  ASAECF_gemm2dot<<<dim3(256), 512, 0, stream>>>(hsl, w2s, ub2, ib2, out);
}